// Round 1
// baseline (40.635 us; speedup 1.0000x reference)
//
#include <hip/hip_runtime.h>
#include <math.h>

// Problem constants (fixed by setup_inputs)
#define RC_F 5.2f
// pi / Rc in float32, matching jnp.pi * d / Rc order closely enough (2% threshold)
#define PI_OVER_RC 0.6041524f

// ---------------------------------------------------------------------------
// Kernel 1: connectivity passthrough, int32 -> float32, vectorized x4
// ---------------------------------------------------------------------------
__global__ __launch_bounds__(256) void APEV_conn_copy(
    const int* __restrict__ conn, float* __restrict__ out, int n)
{
    int i = (blockIdx.x * blockDim.x + threadIdx.x) * 4;
    if (i < n) {
        int4 v = *reinterpret_cast<const int4*>(conn + i);
        float4 f = make_float4((float)v.x, (float)v.y, (float)v.z, (float)v.w);
        *reinterpret_cast<float4*>(out + i) = f;
    }
}

// ---------------------------------------------------------------------------
// Kernel 2: radial terms. 8 threads per edge; each thread computes 4
// consecutive outputs (one float4) of the 32-wide output row.
//   thread t: edge = t>>3, q = t&7
//   outputs k = 4q..4q+3 -> eta index = q>>1 (constant per thread),
//                           shf index = (q&1)*4 + j
// Stores are lane-consecutive float4 -> fully coalesced 1KB/wave.
// ---------------------------------------------------------------------------
__global__ __launch_bounds__(256) void APEV_radial(
    const int* __restrict__ conn,
    const float* __restrict__ coords,   // [B,256,3]
    const float* __restrict__ EtaR,     // [4]
    const float* __restrict__ ShfR,     // [8]
    float* __restrict__ y,              // [N,32]
    int n_edges)
{
    int t = blockIdx.x * blockDim.x + threadIdx.x;
    int edge = t >> 3;
    if (edge >= n_edges) return;
    int q = t & 7;

    int b = edge >> 15;                 // E = 32768 = 2^15 edges per batch

    int2 cd = *reinterpret_cast<const int2*>(conn + edge * 2);

    float4 res;
    if (cd.x == -1) {
        // masked edge: reference produces zeros for this row
        res = make_float4(0.f, 0.f, 0.f, 0.f);
    } else {
        const float* pa = coords + (size_t)(b * 256 + cd.x) * 3;
        const float* pd = coords + (size_t)(b * 256 + cd.y) * 3;
        float dx = pa[0] - pd[0];
        float dy = pa[1] - pd[1];
        float dz = pa[2] - pd[2];
        float d = sqrtf(dx * dx + dy * dy + dz * dz);

        float fc = (d <= RC_F) ? (0.5f * cosf(PI_OVER_RC * d) + 0.5f) : 0.0f;

        if (fc == 0.0f) {
            res = make_float4(0.f, 0.f, 0.f, 0.f);
        } else {
            float eta = EtaR[q >> 1];
            const float* s = ShfR + (q & 1) * 4;
            float c = 0.25f * fc;
            float t0 = d - s[0];
            float t1 = d - s[1];
            float t2 = d - s[2];
            float t3 = d - s[3];
            res.x = c * __expf(-eta * t0 * t0);
            res.y = c * __expf(-eta * t1 * t1);
            res.z = c * __expf(-eta * t2 * t2);
            res.w = c * __expf(-eta * t3 * t3);
        }
    }

    *reinterpret_cast<float4*>(y + (size_t)edge * 32 + q * 4) = res;
}

extern "C" void kernel_launch(void* const* d_in, const int* in_sizes, int n_in,
                              void* d_out, int out_size, void* d_ws, size_t ws_size,
                              hipStream_t stream) {
    const int*   conn   = (const int*)d_in[0];
    const float* coords = (const float*)d_in[1];
    const float* EtaR   = (const float*)d_in[2];
    const float* ShfR   = (const float*)d_in[3];

    float* out = (float*)d_out;

    const int n_conn_elems = in_sizes[0];      // B*E*2 = 2,097,152
    const int n_edges      = n_conn_elems / 2; // 1,048,576
    float* y = out + n_conn_elems;             // y region starts after conn copy

    // connectivity passthrough (int -> float), 4 elems/thread
    {
        int threads = n_conn_elems / 4;
        int blocks = (threads + 255) / 256;
        APEV_conn_copy<<<blocks, 256, 0, stream>>>(conn, out, n_conn_elems);
    }

    // radial terms: 8 threads per edge
    {
        long long total = (long long)n_edges * 8;
        int blocks = (int)((total + 255) / 256);
        APEV_radial<<<blocks, 256, 0, stream>>>(conn, coords, EtaR, ShfR, y, n_edges);
    }
}

// Round 2
// 27.196 us; speedup vs baseline: 1.4942x; 1.4942x over previous
//
#include <hip/hip_runtime.h>
#include <math.h>

// Problem constants (fixed by setup_inputs)
#define RC_F 5.2f
#define PI_OVER_RC 0.6041524f   // pi / Rc in float32

typedef float f4 __attribute__((ext_vector_type(4)));

// ---------------------------------------------------------------------------
// Fused kernel.
//  - All blocks: radial terms, 8 threads per edge; each thread computes one
//    float4 quad of the 32-wide output row. Lane-consecutive float4 stores
//    -> fully coalesced 1 KB/wave, streamed nontemporally.
//  - Blocks [0, conn_blocks): additionally copy connectivity int32->float32,
//    one float4 per thread, nontemporal.
// ---------------------------------------------------------------------------
__global__ __launch_bounds__(256) void APEV_fused(
    const int* __restrict__ conn,
    const float* __restrict__ coords,   // [B,256,3]
    const float* __restrict__ EtaR,     // [4]
    const float* __restrict__ ShfR,     // [8]
    float* __restrict__ out_conn,       // [N*2] as float
    float* __restrict__ y,              // [N,32]
    int n_edges, int conn_blocks, int n_conn_elems)
{
    int t = blockIdx.x * 256 + threadIdx.x;

    // ---- connectivity passthrough (first conn_blocks blocks only) ----
    if (blockIdx.x < conn_blocks) {
        int i = t * 4;
        if (i < n_conn_elems) {
            int4 v = *reinterpret_cast<const int4*>(conn + i);
            f4 f = { (float)v.x, (float)v.y, (float)v.z, (float)v.w };
            __builtin_nontemporal_store(f, reinterpret_cast<f4*>(out_conn + i));
        }
    }

    // ---- radial terms ----
    int edge = t >> 3;
    if (edge >= n_edges) return;
    int q = t & 7;

    int b = edge >> 15;                 // E = 32768 = 2^15 edges per batch

    int2 cd = *reinterpret_cast<const int2*>(conn + edge * 2);

    f4 res;
    if (cd.x == -1) {
        res = (f4){0.f, 0.f, 0.f, 0.f};
    } else {
        const float* pa = coords + (size_t)(b * 256 + cd.x) * 3;
        const float* pd = coords + (size_t)(b * 256 + cd.y) * 3;
        float dx = pa[0] - pd[0];
        float dy = pa[1] - pd[1];
        float dz = pa[2] - pd[2];
        float d = __fsqrt_rn(dx * dx + dy * dy + dz * dz);

        // fast hardware cosine: d/Rc <= 1 here, tiny argument, accuracy ~1e-6
        float fc = (d <= RC_F) ? (0.5f * __cosf(PI_OVER_RC * d) + 0.5f) : 0.0f;

        if (fc == 0.0f) {
            res = (f4){0.f, 0.f, 0.f, 0.f};
        } else {
            float eta = EtaR[q >> 1];
            const float* s = ShfR + (q & 1) * 4;
            float c = 0.25f * fc;
            float t0 = d - s[0];
            float t1 = d - s[1];
            float t2 = d - s[2];
            float t3 = d - s[3];
            res.x = c * __expf(-eta * t0 * t0);
            res.y = c * __expf(-eta * t1 * t1);
            res.z = c * __expf(-eta * t2 * t2);
            res.w = c * __expf(-eta * t3 * t3);
        }
    }

    __builtin_nontemporal_store(res, reinterpret_cast<f4*>(y + (size_t)edge * 32 + q * 4));
}

extern "C" void kernel_launch(void* const* d_in, const int* in_sizes, int n_in,
                              void* d_out, int out_size, void* d_ws, size_t ws_size,
                              hipStream_t stream) {
    const int*   conn   = (const int*)d_in[0];
    const float* coords = (const float*)d_in[1];
    const float* EtaR   = (const float*)d_in[2];
    const float* ShfR   = (const float*)d_in[3];

    float* out = (float*)d_out;

    const int n_conn_elems = in_sizes[0];      // B*E*2 = 2,097,152
    const int n_edges      = n_conn_elems / 2; // 1,048,576
    float* y = out + n_conn_elems;

    // conn copy needs n_conn_elems/4 threads -> blocks of 256
    const int conn_blocks = (n_conn_elems / 4 + 255) / 256;   // 2048

    // radial needs n_edges*8 threads
    long long total = (long long)n_edges * 8;
    int blocks = (int)((total + 255) / 256);                   // 32768

    APEV_fused<<<blocks, 256, 0, stream>>>(conn, coords, EtaR, ShfR,
                                           out, y, n_edges, conn_blocks,
                                           n_conn_elems);
}